// Round 8
// baseline (165.730 us; speedup 1.0000x reference)
//
#include <hip/hip_runtime.h>

typedef _Float16 f16x8 __attribute__((ext_vector_type(8)));
typedef _Float16 f16x2 __attribute__((ext_vector_type(2)));
typedef float    f32x4 __attribute__((ext_vector_type(4)));

#define MFMA(a, b, c) __builtin_amdgcn_mfma_f32_16x16x32_f16((a), (b), (c), 0, 0, 0)

__device__ inline f16x8 zero8() {
    f16x8 z;
#pragma unroll
    for (int i = 0; i < 8; ++i) z[i] = (_Float16)0.0f;
    return z;
}

// R7 structure, restructured into TWO point-tile pairs to cut live VGPRs
// (h1f 64->32, a2 32->16, acc3 16->8): target <=128-VGPR allocation granule.
// R5(124 vgpr)=2 blocks/CU vs R6/R7(144/152)=1 block/CU is the evidence that
// the 128->256 VGPR granule halves occupancy. Weights are re-read from LDS per
// pair (cheap). All fragment maps are the R3-hardware-verified canonical ones
// with the R5-verified absorbed permutation in W2f/W3c pre-packs.
// NEVER use __launch_bounds__(256,2): spill-corrupts MFMA accumulators.
__global__ __launch_bounds__(256, 1)
void DeformationCorrector_78967268704761_kernel(
        const float* __restrict__ F,
        const float* __restrict__ W1, const float* __restrict__ b1,
        const float* __restrict__ W2, const float* __restrict__ b2,
        const float* __restrict__ W3, const float* __restrict__ b3,
        float* __restrict__ out, int N)
{
    __shared__ __align__(16) _Float16 W2f[8][4][64][8];  // 32 KB  b-frags layer2 (absorbed perm)
    __shared__ __align__(16) _Float16 W1f[8][16][8];     // 2 KB   a-frags layer1 (quad0 slice, k=7 -> b1)
    __shared__ __align__(16) _Float16 W3c[4][16][8];     // 1 KB   b-frags layer3 (n<4 compacted)
    __shared__ __align__(16) _Float16 scr[4][2304];      // 18 KB  per-wave: inv(512) | h2(1280) | x(512)

    const int tid  = threadIdx.x;
    const int lane = tid & 63;
    const int w    = tid >> 6;
    const int l15  = tid & 15;
    const int quad = (tid >> 4) & 3;

    _Float16* const invp = &scr[w][0];            // 64 rows x 8 f16 (1 KB)
    _Float16* const h2p  = &scr[w][512];          // 32 rows x 40 f16 (2.5 KB), 80 B row stride
    float*    const xf   = (float*)&scr[w][1792]; // 64 rows x 4 f32 (1 KB)

    // ---------------- weight pre-pack (once per block) ----------------
    for (int m = tid; m < 128 * 128; m += 256) {        // W2[c][n] -> frag layout (absorbed perm)
        int c = m >> 7, n = m & 127;
        int ks = c >> 5, rem = c & 31;
        int j = ((rem >> 4) & 1) * 4 + (rem & 3);
        int q = (rem >> 2) & 3;
        W2f[n >> 4][ks][q * 16 + (n & 15)][j] = (_Float16)W2[m];
    }
    for (int f = tid; f < 1024; f += 256) {             // W1^T a-frags + b1 at k=7
        int mt = f >> 7, l = (f >> 3) & 15, j = f & 7;
        int ch = mt * 16 + l;
        W1f[mt][l][j] = (_Float16)((j < 7) ? W1[j * 128 + ch] : b1[ch]);
    }
    for (int f = tid; f < 512; f += 256) {              // W3 b-frags (h2 col space c''=2*l+(nt2&1))
        int c2 = f >> 2, n3 = f & 3;
        int nt2 = c2 >> 4, l = c2 & 15;
        int s = nt2 >> 1, ch = l * 2 + (nt2 & 1);
        W3c[s][(ch >> 3) * 4 + n3][ch & 7] = (_Float16)W3[c2 * 4 + n3];
    }
    float b2r[8];
#pragma unroll
    for (int nt = 0; nt < 8; ++nt) b2r[nt] = b2[nt * 16 + l15];
    const float b3v = (l15 < 4) ? b3[l15] : 0.f;
    __syncthreads();   // only barrier; main loop LDS traffic is wave-private

    const int ntiles = (N + 255) >> 8;
    for (int tile = blockIdx.x; tile < ntiles; tile += (int)gridDim.x) {
        const int p = tile * 256 + tid;

        // ---------------- phase A: polar + invariants (fp32) ----------------
        float a, b, c, d;
        if (p < N) {
            const float4 f4 = *(const float4*)(F + 4ll * p);
            a = f4.x; b = f4.y; c = f4.z; d = f4.w;
        } else { a = 1.f; b = 0.f; c = 0.f; d = 1.f; }
        const float x1 = a + d, y1 = c - b, x2 = a - d, y2 = c + b;
        const float h1v = sqrtf(x1 * x1 + y1 * y1);
        const float h2v = sqrtf(x2 * x2 + y2 * y2);
        const float s1 = 0.5f * (h1v + h2v), s2 = 0.5f * (h1v - h2v);
        const float ir = 1.0f / h1v;              // h1v ~ 2 (det F > 0)
        const float Rc = x1 * ir, Rs = y1 * ir;   // R = [[Rc,-Rs],[Rs,Rc]]
        f16x8 iv;
        iv[0] = (_Float16)(s1 - 1.f);
        iv[1] = (_Float16)(s2 - 1.f);
        iv[2] = (_Float16)(a * a + c * c - 1.f);
        const float i3 = a * b + c * d;
        iv[3] = (_Float16)i3;
        iv[4] = (_Float16)i3;
        iv[5] = (_Float16)(b * b + d * d - 1.f);
        iv[6] = (_Float16)(a * d - b * c - 1.f);
        iv[7] = (_Float16)1.0f;                    // bias channel
        *(f16x8*)(&invp[lane * 8]) = iv;

        // ---------------- two point-tile pairs: nt = 2*pair + ntl ----------------
        for (int pair = 0; pair < 2; ++pair) {
            // layer 1 (transposed): h1 for this pair kept in regs
            f16x8 binv[2];
#pragma unroll
            for (int ntl = 0; ntl < 2; ++ntl)
                binv[ntl] = (quad == 0)
                    ? *(const f16x8*)(&invp[((pair * 2 + ntl) * 16 + l15) * 8])
                    : zero8();
            f16x8 h1f[2][4];   // [ntl][ks] = layer-2 A-fragments
#pragma unroll
            for (int mt = 0; mt < 8; ++mt) {
                const f16x8 af = (quad == 0) ? *(const f16x8*)(&W1f[mt][l15][0]) : zero8();
#pragma unroll
                for (int ntl = 0; ntl < 2; ++ntl) {
                    f32x4 cz = {0.f, 0.f, 0.f, 0.f};
                    const f32x4 cc = MFMA(af, binv[ntl], cz);
#pragma unroll
                    for (int r = 0; r < 4; ++r)
                        h1f[ntl][mt >> 1][(mt & 1) * 4 + r] = (_Float16)fmaxf(cc[r], 0.f);
                }
            }

            // layers 2+3 interleaved for this pair
            f32x4 acc3[2];
#pragma unroll
            for (int ntl = 0; ntl < 2; ++ntl) acc3[ntl] = (f32x4){0.f, 0.f, 0.f, 0.f};

#pragma unroll
            for (int s = 0; s < 4; ++s) {
                f32x4 a2[2][2];
#pragma unroll
                for (int h = 0; h < 2; ++h)
#pragma unroll
                    for (int ntl = 0; ntl < 2; ++ntl)
                        a2[h][ntl] = (f32x4){0.f, 0.f, 0.f, 0.f};
#pragma unroll
                for (int h = 0; h < 2; ++h) {
                    const int nt2 = 2 * s + h;
#pragma unroll
                    for (int ks = 0; ks < 4; ++ks) {
                        const f16x8 bf = *(const f16x8*)(&W2f[nt2][ks][lane][0]);
#pragma unroll
                        for (int ntl = 0; ntl < 2; ++ntl)
                            a2[h][ntl] = MFMA(h1f[ntl][ks], bf, a2[h][ntl]);
                    }
                }
                // bias + relu + transpose 2 channel-tiles into per-wave slice
                const float bb0 = b2r[2 * s], bb1 = b2r[2 * s + 1];
#pragma unroll
                for (int ntl = 0; ntl < 2; ++ntl) {
#pragma unroll
                    for (int r = 0; r < 4; ++r) {
                        f16x2 pw;
                        pw[0] = (_Float16)fmaxf(a2[0][ntl][r] + bb0, 0.f);
                        pw[1] = (_Float16)fmaxf(a2[1][ntl][r] + bb1, 0.f);
                        *(f16x2*)(&h2p[(ntl * 16 + quad * 4 + r) * 40 + l15 * 2]) = pw;
                    }
                }
                // layer-3 partial K (32 channels of this slice)
                const f16x8 bw3 = (l15 < 4) ? *(const f16x8*)(&W3c[s][quad * 4 + l15][0])
                                            : zero8();
#pragma unroll
                for (int ntl = 0; ntl < 2; ++ntl) {
                    const f16x8 ah = *(const f16x8*)(&h2p[(ntl * 16 + l15) * 40 + quad * 8]);
                    acc3[ntl] = MFMA(ah, bw3, acc3[ntl]);
                }
            }

            // stash x for this pair's 32 points
#pragma unroll
            for (int ntl = 0; ntl < 2; ++ntl)
#pragma unroll
                for (int r = 0; r < 4; ++r)
                    if (l15 < 4)
                        xf[(pair * 32 + ntl * 16 + quad * 4 + r) * 4 + l15] =
                            acc3[ntl][r] + b3v;
        }

        // ---------------- epilogue: x -> symmetrize -> R@x + F ----------------
        const float4 xv = *(const float4*)(&xf[lane * 4]);
        const float xm  = 0.5f * (xv.y + xv.z);
        const float d00 = Rc * xv.x - Rs * xm;
        const float d01 = Rc * xm   - Rs * xv.w;
        const float d10 = Rs * xv.x + Rc * xm;
        const float d11 = Rs * xm   + Rc * xv.w;
        if (p < N) {
            float4 o;
            o.x = a + d00; o.y = b + d01; o.z = c + d10; o.w = d + d11;
            *(float4*)(out + 4ll * p) = o;
        }
    }
}

extern "C" void kernel_launch(void* const* d_in, const int* in_sizes, int n_in,
                              void* d_out, int out_size, void* d_ws, size_t ws_size,
                              hipStream_t stream) {
    const float* F  = (const float*)d_in[0];
    const float* W1 = (const float*)d_in[1];
    const float* b1 = (const float*)d_in[2];
    const float* W2 = (const float*)d_in[3];
    const float* b2 = (const float*)d_in[4];
    const float* W3 = (const float*)d_in[5];
    const float* b3 = (const float*)d_in[6];
    float* out = (float*)d_out;
    const int N = in_sizes[0] / 4;
    const int ntiles = (N + 255) / 256;
    const int grid = ntiles < 1024 ? ntiles : 1024;
    DeformationCorrector_78967268704761_kernel<<<grid, 256, 0, stream>>>(
        F, W1, b1, W2, b2, W3, b3, out, N);
}

// Round 10
// 142.245 us; speedup vs baseline: 1.1651x; 1.1651x over previous
//
#include <hip/hip_runtime.h>

typedef _Float16 f16x8 __attribute__((ext_vector_type(8)));
typedef _Float16 f16x2 __attribute__((ext_vector_type(2)));
typedef float    f32x4 __attribute__((ext_vector_type(4)));

#define MFMA(a, b, c) __builtin_amdgcn_mfma_f32_16x16x32_f16((a), (b), (c), 0, 0, 0)

__device__ inline f16x8 zero8() {
    f16x8 z;
#pragma unroll
    for (int i = 0; i < 8; ++i) z[i] = (_Float16)0.0f;
    return z;
}

// R5 consolidation build. R5 (this exact structure, (256,1)) = 85us counter,
// VGPR 124 + 128 acc = 252 total -> 2 waves/SIMD. Changes vs R5:
//   (1) grid 1024 -> 512 (= 2 blocks/CU x 256 CU): one block generation,
//       weight pre-pack paid once per resident slot.
//   (2) next-tile F float4 prefetch issued at top of body (+4 VGPR, 252->256).
// BAN: any __launch_bounds__ min-waves >= 2 — 5/5 such builds miscompiled
// (absmax 0.04-0.09: R1,R2,R4,R9) while the identical (256,1) builds passed.
// Fragment maps: R3-hardware-verified canonical; A-frag k=(lane>>4)*8+j,
// B-frag k=(lane>>4)*8+j / n=lane&15, D m=(lane>>4)*4+r / n=lane&15.
__global__ __launch_bounds__(256, 1)
void DeformationCorrector_78967268704761_kernel(
        const float* __restrict__ F,
        const float* __restrict__ W1, const float* __restrict__ b1,
        const float* __restrict__ W2, const float* __restrict__ b2,
        const float* __restrict__ W3, const float* __restrict__ b3,
        float* __restrict__ out, int N)
{
    __shared__ __align__(16) _Float16 W2f[8][4][64][8];   // 32 KB canonical b-frags (verified R3)
    __shared__ __align__(16) _Float16 W1f[8][16][8];      // 2 KB  layer1 B-frags, lanes<16 (k<8)
    __shared__ __align__(16) _Float16 W3c[4][16][8];      // 1 KB  layer3 B-frags, compacted n<4
    __shared__ __align__(16) _Float16 invL[256][8];       // 4 KB  per-point invariants
    __shared__ __align__(16) _Float16 scratch[4][64][40]; // 20 KB per-wave h slice (also xls alias)

    const int tid  = threadIdx.x;
    const int lane = tid & 63;
    const int w    = tid >> 6;
    const int l15  = tid & 15;
    const int quad = (tid >> 4) & 3;

    // ---------------- weight pre-pack (once per block) ----------------
    for (int m = tid; m < 128 * 128; m += 256) {          // W2[k][n] -> canonical frag (R3-verified)
        int k = m >> 7, n = m & 127;
        W2f[n >> 4][k >> 5][((k >> 3) & 3) * 16 + (n & 15)][k & 7] = (_Float16)W2[m];
    }
    for (int f = tid; f < 1024; f += 256) {               // W1 b-frags: B[k=j][n], k=7 -> b1
        int nt = f >> 7, n15 = (f >> 3) & 15, j = f & 7;
        W1f[nt][n15][j] = (_Float16)((j < 7) ? W1[j * 128 + nt * 16 + n15]
                                             : b1[nt * 16 + n15]);
    }
    for (int f = tid; f < 512; f += 256) {                // W3 b-frags canonical, lanes q*4+n
        int s = f >> 7, idx = (f >> 3) & 15, j = f & 7;
        int q = idx >> 2, n = idx & 3;
        W3c[s][idx][j] = (_Float16)W3[(s * 32 + q * 8 + j) * 4 + n];
    }
    float b2r[8];
#pragma unroll
    for (int nt = 0; nt < 8; ++nt) b2r[nt] = b2[nt * 16 + l15];
    const float b3v = (l15 < 4) ? b3[l15] : 0.f;
    __syncthreads();   // only barrier; all main-loop LDS traffic is wave-private

    const int ntiles = (N + 255) >> 8;
    const int stride = (int)gridDim.x;

    // prime the F prefetch for the first tile
    float a, b, c, d;
    {
        const int p0 = blockIdx.x * 256 + tid;
        if (blockIdx.x < ntiles && p0 < N) {
            const float4 f4 = *(const float4*)(F + 4ll * p0);
            a = f4.x; b = f4.y; c = f4.z; d = f4.w;
        } else { a = 1.f; b = 0.f; c = 0.f; d = 1.f; }
    }

    for (int tile = blockIdx.x; tile < ntiles; tile += stride) {
        // ---------------- prefetch next tile's F (overlaps whole body) ----------------
        float na = 1.f, nb = 0.f, nc = 0.f, nd = 1.f;
        {
            const int pn = (tile + stride) * 256 + tid;
            if (tile + stride < ntiles && pn < N) {
                const float4 f4 = *(const float4*)(F + 4ll * pn);
                na = f4.x; nb = f4.y; nc = f4.z; nd = f4.w;
            }
        }
        const int p = tile * 256 + tid;

        // ---------------- invariants + polar (fp32, verified) ----------------
        const float x1 = a + d, y1 = c - b, x2 = a - d, y2 = c + b;
        const float h1v = sqrtf(x1 * x1 + y1 * y1);
        const float h2v = sqrtf(x2 * x2 + y2 * y2);
        const float s1 = 0.5f * (h1v + h2v), s2 = 0.5f * (h1v - h2v);
        const float ir = 1.0f / h1v;
        const float Rc = x1 * ir, Rs = y1 * ir;
        f16x8 iv;
        iv[0] = (_Float16)(s1 - 1.f);
        iv[1] = (_Float16)(s2 - 1.f);
        iv[2] = (_Float16)(a * a + c * c - 1.f);
        const float i3 = a * b + c * d;
        iv[3] = (_Float16)i3;
        iv[4] = (_Float16)i3;
        iv[5] = (_Float16)(b * b + d * d - 1.f);
        iv[6] = (_Float16)(a * d - b * c - 1.f);
        iv[7] = (_Float16)1.0f;
        *(f16x8*)(&invL[tid][0]) = iv;

        // inv A-frags: A[m=l15][k=quad*8+j], nonzero only quad==0 (k<8)
        f16x8 binv[4];
#pragma unroll
        for (int mt = 0; mt < 4; ++mt)
            binv[mt] = (quad == 0) ? *(const f16x8*)(&invL[w * 64 + mt * 16 + l15][0])
                                   : zero8();

        // ---------------- layers 1+2 per 32-channel chunk ----------------
        f32x4 acc2[8][4];   // [nt2][mt2]
#pragma unroll
        for (int nt2 = 0; nt2 < 8; ++nt2)
#pragma unroll
            for (int mt2 = 0; mt2 < 4; ++mt2) acc2[nt2][mt2] = (f32x4){0.f, 0.f, 0.f, 0.f};

        for (int ks = 0; ks < 4; ++ks) {
            // layer-1 MFMA: h1[pt][ch] for ch in [ks*32, ks*32+32)
#pragma unroll
            for (int h = 0; h < 2; ++h) {
                const f16x8 bw1 = (lane < 16) ? *(const f16x8*)(&W1f[2 * ks + h][l15][0])
                                              : zero8();
#pragma unroll
                for (int mt = 0; mt < 4; ++mt) {
                    f32x4 cz = {0.f, 0.f, 0.f, 0.f};
                    const f32x4 cc = MFMA(binv[mt], bw1, cz);
                    // D[pt = mt*16+quad*4+r][ch_local = h*16+l15] -> relu -> scratch
#pragma unroll
                    for (int r = 0; r < 4; ++r)
                        scratch[w][mt * 16 + quad * 4 + r][h * 16 + l15] =
                            (_Float16)fmaxf(cc[r], 0.f);
                }
            }
            // layer-2: canonical a-frags from slice + canonical W2 b-frags
            f16x8 af[4];
#pragma unroll
            for (int mt2 = 0; mt2 < 4; ++mt2)
                af[mt2] = *(const f16x8*)(&scratch[w][mt2 * 16 + l15][quad * 8]);
#pragma unroll
            for (int nt2 = 0; nt2 < 8; ++nt2) {
                const f16x8 bf = *(const f16x8*)(&W2f[nt2][ks][lane][0]);
#pragma unroll
                for (int mt2 = 0; mt2 < 4; ++mt2)
                    acc2[nt2][mt2] = MFMA(af[mt2], bf, acc2[nt2][mt2]);
            }
        }

        // ---------------- layer 3 per 32-channel chunk (MFMA) ----------------
        f32x4 acc3[4];
#pragma unroll
        for (int mt2 = 0; mt2 < 4; ++mt2) acc3[mt2] = (f32x4){0.f, 0.f, 0.f, 0.f};

#pragma unroll
        for (int s = 0; s < 4; ++s) {
#pragma unroll
            for (int h = 0; h < 2; ++h) {
                const int nt2 = 2 * s + h;
                const float bb = b2r[nt2];
#pragma unroll
                for (int mt2 = 0; mt2 < 4; ++mt2)
#pragma unroll
                    for (int r = 0; r < 4; ++r)
                        scratch[w][mt2 * 16 + quad * 4 + r][h * 16 + l15] =
                            (_Float16)fmaxf(acc2[nt2][mt2][r] + bb, 0.f);
            }
            const f16x8 bw3 = (l15 < 4) ? *(const f16x8*)(&W3c[s][quad * 4 + l15][0])
                                        : zero8();
#pragma unroll
            for (int mt2 = 0; mt2 < 4; ++mt2) {
                const f16x8 ah = *(const f16x8*)(&scratch[w][mt2 * 16 + l15][quad * 8]);
                acc3[mt2] = MFMA(ah, bw3, acc3[mt2]);
            }
        }

        // ---------------- epilogue: x via scratch alias -> R@x + F ----------------
        float* xf = (float*)(&scratch[w][0][0]);   // 1 KB of the 5 KB wave slice
#pragma unroll
        for (int mt2 = 0; mt2 < 4; ++mt2)
#pragma unroll
            for (int r = 0; r < 4; ++r)
                if (l15 < 4)
                    xf[(mt2 * 16 + quad * 4 + r) * 4 + l15] = acc3[mt2][r] + b3v;

        const float4 xv = *(const float4*)(&xf[lane * 4]);
        const float xm  = 0.5f * (xv.y + xv.z);
        const float d00 = Rc * xv.x - Rs * xm;
        const float d01 = Rc * xm   - Rs * xv.w;
        const float d10 = Rs * xv.x + Rc * xm;
        const float d11 = Rs * xm   + Rc * xv.w;
        if (p < N) {
            float4 o;
            o.x = a + d00; o.y = b + d01; o.z = c + d10; o.w = d + d11;
            *(float4*)(out + 4ll * p) = o;
        }

        // rotate prefetched F into place for the next tile
        a = na; b = nb; c = nc; d = nd;
    }
}

extern "C" void kernel_launch(void* const* d_in, const int* in_sizes, int n_in,
                              void* d_out, int out_size, void* d_ws, size_t ws_size,
                              hipStream_t stream) {
    const float* F  = (const float*)d_in[0];
    const float* W1 = (const float*)d_in[1];
    const float* b1 = (const float*)d_in[2];
    const float* W2 = (const float*)d_in[3];
    const float* b2 = (const float*)d_in[4];
    const float* W3 = (const float*)d_in[5];
    const float* b3 = (const float*)d_in[6];
    float* out = (float*)d_out;
    const int N = in_sizes[0] / 4;
    const int ntiles = (N + 255) / 256;
    const int grid = ntiles < 512 ? ntiles : 512;   // 2 blocks/CU x 256 CU: one generation
    DeformationCorrector_78967268704761_kernel<<<grid, 256, 0, stream>>>(
        F, W1, b1, W2, b2, W3, b3, out, N);
}